// Round 11
// baseline (538.796 us; speedup 1.0000x reference)
//
#include <hip/hip_runtime.h>

#define EPSV 1e-5f

typedef __attribute__((ext_vector_type(8))) short short8;
typedef __attribute__((ext_vector_type(4))) float float4v;

static inline int cdiv(int a, int b) { return (a + b - 1) / b; }

__device__ inline unsigned short f2bf(float x) {
  unsigned u = __float_as_uint(x);
  return (unsigned short)((u + 0x7FFFu + ((u >> 16) & 1u)) >> 16);
}
__device__ inline float bf2f(unsigned short u) {
  return __uint_as_float(((unsigned)u) << 16);
}

#define NBUCKET 64

struct PrepArgs {
  const float* w[10];
  unsigned short* wt[10];
  int ci[10];
  int co[10];
  int wcum[11];
  const float* feats;
  unsigned short* featsb;
  int nfeat4;
  float* stats;
};

// zero stats + feats fp32->bf16 + all 10 weights fp32->bf16 transposed [27][CO][CI]
__global__ __launch_bounds__(256) void prep_kernel(PrepArgs p) {
  long tid = (long)blockIdx.x * 256 + threadIdx.x;
  const int nstat4 = 10 * NBUCKET * 128 / 4;
  if (tid < nstat4) {
    ((float4*)p.stats)[tid] = make_float4(0.f, 0.f, 0.f, 0.f);
    return;
  }
  tid -= nstat4;
  if (tid < p.nfeat4) {
    float4 v = ((const float4*)p.feats)[tid];
    ushort4 r;
    r.x = f2bf(v.x); r.y = f2bf(v.y); r.z = f2bf(v.z); r.w = f2bf(v.w);
    ((ushort4*)p.featsb)[tid] = r;
    return;
  }
  tid -= p.nfeat4;
  if (tid >= p.wcum[10]) return;
  int i = 0;
  while (tid >= p.wcum[i + 1]) ++i;
  int e = (int)(tid - p.wcum[i]);
  int ci = p.ci[i], co = p.co[i];
  int k = e / (ci * co);
  int r = e - k * (ci * co);
  int o = r / ci;
  int c = r - o * ci;
  p.wt[i][((long)k * co + o) * ci + c] = f2bf(p.w[i][((long)k * ci + c) * co + o]);
}

// ================= MFMA gather-GEMM conv =================
// Block = 4 waves = 64 output rows x one 16-cout slice (blockIdx.y).
// nbr indices staged with fully-coalesced block loads (108 lines/block instead
// of ~300 scattered lines/wave), LDS stride 29 to avoid bank aliasing. A/B
// gathers stay register-resident for memory-level parallelism.
template<int CI, int CO>
__global__ __launch_bounds__(256) void conv_mfma(
    const unsigned short* __restrict__ f, const int* __restrict__ nbr,
    const unsigned short* __restrict__ wt, unsigned short* __restrict__ y,
    float* __restrict__ stats, int nout, int nxb) {
  constexpr int NCHUNK = (CI == 8) ? 7 : (CI == 16) ? 14 : (CI == 32) ? 27 : 54;
  __shared__ int sIdx[64 * 29];

  // XCD-contiguous swizzle
  int bx = blockIdx.x, xb;
  {
    int S8 = nxb >> 3;
    if (bx < (S8 << 3)) xb = (bx & 7) * S8 + (bx >> 3);
    else xb = bx;
  }

  const int tid = threadIdx.x;
  const int lane = tid & 63;
  const int wid = tid >> 6;
  const int m = lane & 15;
  const int quad = lane >> 4;
  const int blockrow = xb * 64;
  const int rloc = wid * 16 + m;
  const int cbase = blockIdx.y * 16;
  const int co = cbase + m;
  const bool cok = co < CO;

  // ---- coalesced nbr staging: 1728 contiguous dwords ----
  {
    const long limit = (long)nout * 27;
#pragma unroll
    for (int j = 0; j < 7; ++j) {
      int off = j * 256 + tid;
      if (off < 64 * 27) {
        int r = off / 27;
        int t = off - r * 27;
        long gaddr = (long)blockrow * 27 + off;
        sIdx[r * 29 + t] = (gaddr < limit) ? nbr[gaddr] : -1;
      }
    }
  }
  __syncthreads();

  auto tapof = [&](int c) -> int {
    if constexpr (CI == 8) return c * 4 + quad;
    else if constexpr (CI == 16) return c * 2 + (quad >> 1);
    else if constexpr (CI == 32) return c;
    else return c >> 1;
  };
  auto cioof = [&](int c) -> int {
    if constexpr (CI == 8) return 0;
    else if constexpr (CI == 16) return (quad & 1) * 8;
    else if constexpr (CI == 32) return quad * 8;
    else return ((c & 1) << 5) + quad * 8;
  };

  float4v acc = {0.f, 0.f, 0.f, 0.f};

  if constexpr (CI <= 16) {
    int idxs[NCHUNK];
#pragma unroll
    for (int c = 0; c < NCHUNK; ++c) {
      int tap = tapof(c);
      idxs[c] = (tap < 27) ? sIdx[rloc * 29 + tap] : -1;
    }
    short8 A[NCHUNK], B[NCHUNK];
#pragma unroll
    for (int c = 0; c < NCHUNK; ++c) {
      int tap = tapof(c);
      short8 a, bq;
#pragma unroll
      for (int q = 0; q < 8; ++q) { a[q] = 0; bq[q] = 0; }
      if (idxs[c] >= 0) a = *(const short8*)(f + (long)idxs[c] * CI + cioof(c));
      if (cok && tap < 27) bq = *(const short8*)(wt + ((long)tap * CO + co) * CI + cioof(c));
      A[c] = a; B[c] = bq;
    }
#pragma unroll
    for (int c = 0; c < NCHUNK; ++c)
      acc = __builtin_amdgcn_mfma_f32_16x16x32_bf16(A[c], B[c], acc, 0, 0, 0);
  } else {
    constexpr int G = 9;
    constexpr int NG = NCHUNK / G;
    int idxs[27];
#pragma unroll
    for (int t = 0; t < 27; ++t)
      idxs[t] = sIdx[rloc * 29 + t];

    short8 A[2][G], B[2][G];
    auto load_group = [&](int g, int bi) {
#pragma unroll
      for (int j = 0; j < G; ++j) {
        const int c = g * G + j;
        const int tap = tapof(c);
        short8 a, bq;
#pragma unroll
        for (int q = 0; q < 8; ++q) { a[q] = 0; bq[q] = 0; }
        int idx = idxs[tap];
        if (idx >= 0) a = *(const short8*)(f + (long)idx * CI + cioof(c));
        if (cok) bq = *(const short8*)(wt + ((long)tap * CO + co) * CI + cioof(c));
        A[bi][j] = a; B[bi][j] = bq;
      }
    };
    load_group(0, 0);
#pragma unroll
    for (int g = 0; g < NG; ++g) {
      const int cur = g & 1;
      if (g + 1 < NG) load_group(g + 1, cur ^ 1);
#pragma unroll
      for (int j = 0; j < G; ++j)
        acc = __builtin_amdgcn_mfma_f32_16x16x32_bf16(A[cur][j], B[cur][j], acc, 0, 0, 0);
    }
  }

  // D layout: col = lane&15 (cout), row = quad*4 + r
  float sum = 0.f, sq = 0.f;
#pragma unroll
  for (int r = 0; r < 4; ++r) {
    float v = acc[r];
    int orow = blockrow + wid * 16 + quad * 4 + r;
    if (cok && orow < nout) y[(long)orow * CO + co] = f2bf(v);
    sum += v;
    sq = fmaf(v, v, sq);
  }
  sum += __shfl_xor(sum, 16); sq += __shfl_xor(sq, 16);
  sum += __shfl_xor(sum, 32); sq += __shfl_xor(sq, 32);
  if (quad == 0 && cok) {
    float* st = stats + (((unsigned)xb & (NBUCKET - 1)) << 7);
    atomicAdd(&st[co], sum);
    atomicAdd(&st[64 + co], sq);
  }
}

// ---- BN+ReLU (+bf16 skip), bf16 y -> bf16 feature map ----
template<int CO>
__global__ __launch_bounds__(256) void bn_relu_bf16(
    const unsigned short* __restrict__ y, const float* __restrict__ stats,
    const float* __restrict__ g, const float* __restrict__ b,
    const unsigned short* __restrict__ skip, unsigned short* __restrict__ out,
    int nout, float inv_n) {
  __shared__ float sA[CO], sC[CO];
  if ((int)threadIdx.x < CO) {
    int o = threadIdx.x;
    float su = 0.f, sq = 0.f;
#pragma unroll 8
    for (int bk = 0; bk < NBUCKET; ++bk) {
      su += stats[bk * 128 + o];
      sq += stats[bk * 128 + 64 + o];
    }
    float mu = su * inv_n;
    float var = sq * inv_n - mu * mu;
    float a = g[o] * rsqrtf(var + EPSV);
    sA[o] = a;
    sC[o] = fmaf(-mu, a, b[o]);
  }
  __syncthreads();
  long i4 = (long)blockIdx.x * 256 + threadIdx.x;
  long total4 = (long)nout * CO / 4;
  if (i4 >= total4) return;
  int o = (int)((i4 * 4) % CO);
  ushort4 v = ((const ushort4*)y)[i4];
  float vv[4] = {bf2f(v.x), bf2f(v.y), bf2f(v.z), bf2f(v.w)};
  unsigned short rr[4];
#pragma unroll
  for (int j = 0; j < 4; ++j) {
    float x = fmaxf(fmaf(vv[j], sA[o + j], sC[o + j]), 0.f);
    if (skip) x += bf2f(skip[i4 * 4 + j]);
    rr[j] = f2bf(x);
  }
  ushort4 r;
  r.x = rr[0]; r.y = rr[1]; r.z = rr[2]; r.w = rr[3];
  ((ushort4*)out)[i4] = r;
}

// ---- fused tail: x0 = c0f + relu(bn(y9)); out0 = x0 @ lin_w.T ----
__global__ __launch_bounds__(256) void tail_kernel(
    const unsigned short* __restrict__ c0f, const float* __restrict__ st9,
    const float* __restrict__ g9, const float* __restrict__ b9, float inv_n,
    const float* __restrict__ lin_w, const unsigned short* __restrict__ y9,
    float* __restrict__ out0, float* __restrict__ x0, int n0) {
  __shared__ float swl[64];
  __shared__ float sbn[16];
  if (threadIdx.x < 64) swl[threadIdx.x] = lin_w[threadIdx.x];
  if (threadIdx.x < 8) {
    int o = threadIdx.x;
    float su = 0.f, sq = 0.f;
#pragma unroll 8
    for (int bk = 0; bk < NBUCKET; ++bk) {
      su += st9[bk * 128 + o];
      sq += st9[bk * 128 + 64 + o];
    }
    float mu = su * inv_n;
    float var = sq * inv_n - mu * mu;
    float a = g9[o] * rsqrtf(var + EPSV);
    sbn[o] = a;
    sbn[8 + o] = fmaf(-mu, a, b9[o]);
  }
  __syncthreads();
  int n = blockIdx.x * 256 + threadIdx.x;
  if (n >= n0) return;
  const ushort4* pr = (const ushort4*)(y9 + (long)n * 8);
  ushort4 r0 = pr[0], r1 = pr[1];
  unsigned short rw[8] = {r0.x, r0.y, r0.z, r0.w, r1.x, r1.y, r1.z, r1.w};
  const ushort4* pc = (const ushort4*)(c0f + (long)n * 8);
  ushort4 c0 = pc[0], c1 = pc[1];
  unsigned short cs[8] = {c0.x, c0.y, c0.z, c0.w, c1.x, c1.y, c1.z, c1.w};
  float xv[8];
#pragma unroll
  for (int c = 0; c < 8; ++c)
    xv[c] = bf2f(cs[c]) + fmaxf(fmaf(bf2f(rw[c]), sbn[c], sbn[8 + c]), 0.f);
  *(float4*)(x0 + (long)n * 8) = make_float4(xv[0], xv[1], xv[2], xv[3]);
  *(float4*)(x0 + (long)n * 8 + 4) = make_float4(xv[4], xv[5], xv[6], xv[7]);
  float ov[8];
#pragma unroll
  for (int j = 0; j < 8; ++j) {
    float s = 0.f;
#pragma unroll
    for (int c = 0; c < 8; ++c) s = fmaf(xv[c], swl[j * 8 + c], s);
    ov[j] = s;
  }
  *(float4*)(out0 + (long)n * 8) = make_float4(ov[0], ov[1], ov[2], ov[3]);
  *(float4*)(out0 + (long)n * 8 + 4) = make_float4(ov[4], ov[5], ov[6], ov[7]);
}

extern "C" void kernel_launch(void* const* d_in, const int* in_sizes, int n_in,
                              void* d_out, int out_size, void* d_ws, size_t ws_size,
                              hipStream_t stream) {
  const float* feats   = (const float*)d_in[0];
  const int* nbr0      = (const int*)d_in[1];
  const int* nbr_d01   = (const int*)d_in[2];
  const int* nbr1      = (const int*)d_in[3];
  const int* nbr_d12   = (const int*)d_in[4];
  const int* nbr2      = (const int*)d_in[5];
  const int* nbr_d23   = (const int*)d_in[6];
  const int* nbr3      = (const int*)d_in[7];
  const int* nbr_u32   = (const int*)d_in[8];
  const int* nbr_u21   = (const int*)d_in[9];
  const int* nbr_u10   = (const int*)d_in[10];
  const float* w[10];
  const float* g[10];
  const float* b[10];
  for (int i = 0; i < 10; ++i) {
    w[i] = (const float*)d_in[11 + 3 * i];
    g[i] = (const float*)d_in[12 + 3 * i];
    b[i] = (const float*)d_in[13 + 3 * i];
  }
  const float* lin_w = (const float*)d_in[41];

  const int N0 = in_sizes[0] / 16;
  const int N1 = in_sizes[2] / 27;
  const int N2 = in_sizes[4] / 27;
  const int N3 = in_sizes[6] / 27;
  const float i0 = 1.f / N0, i1 = 1.f / N1, i2 = 1.f / N2, i3 = 1.f / N3;

  static const int CIv[10] = {16, 8, 16, 16, 32, 32, 64, 64, 32, 16};
  static const int COv[10] = {8, 16, 16, 32, 32, 64, 64, 32, 16, 8};

  // ---- workspace: fp32 stats region, then bf16 (ushort) region ----
  float* stats = (float*)d_ws;                       // 10 x NBUCKET x 128 floats
  unsigned short* u = (unsigned short*)(stats + 10 * NBUCKET * 128);

  unsigned short* yraw = u; u += (size_t)N1 * 32;    // bf16 y scratch

  unsigned short* wt[10];
  int wcum[11];
  wcum[0] = 0;
  for (int i = 0; i < 10; ++i) {
    wt[i] = u;
    int sz = 27 * CIv[i] * COv[i];
    u += sz;
    wcum[i + 1] = wcum[i] + sz;
  }
  unsigned short* featsb = u; u += (size_t)N0 * 16;
  unsigned short* c0f = u;    u += (size_t)N0 * 8;
  unsigned short* t1  = u;    u += (size_t)N1 * 16;
  unsigned short* c2f = u;    u += (size_t)N1 * 16;
  unsigned short* t2  = u;    u += (size_t)N2 * 32;
  unsigned short* c4f = u;    u += (size_t)N2 * 32;
  unsigned short* t3  = u;    u += (size_t)N3 * 64;
  unsigned short* t4  = u;    u += (size_t)N3 * 64;
  unsigned short* t5  = t2;   // reuse
  unsigned short* t6  = t1;   // reuse
  float* out0 = (float*)d_out;
  float* x0   = (float*)d_out + (size_t)N0 * 8;

  float* s[10];
  for (int i = 0; i < 10; ++i) s[i] = stats + i * NBUCKET * 128;

  // ---- prep: zero stats, feats->bf16, weights->bf16 transposed ----
  PrepArgs pa;
  for (int i = 0; i < 10; ++i) {
    pa.w[i] = w[i]; pa.wt[i] = wt[i];
    pa.ci[i] = CIv[i]; pa.co[i] = COv[i];
    pa.wcum[i] = wcum[i];
  }
  pa.wcum[10] = wcum[10];
  pa.feats = feats; pa.featsb = featsb;
  pa.nfeat4 = N0 * 16 / 4;
  pa.stats = stats;
  long prep_total = (10 * NBUCKET * 128 / 4) + pa.nfeat4 + wcum[10];
  prep_kernel<<<(int)((prep_total + 255) / 256), 256, 0, stream>>>(pa);

  auto bgrid = [](long nout, int co) { return (int)((nout * co / 4 + 255) / 256); };

  int xb0 = cdiv(N0, 64), xb1 = cdiv(N1, 64), xb2 = cdiv(N2, 64), xb3 = cdiv(N3, 64);

  // conv0: 16->8 @ N0
  conv_mfma<16, 8><<<dim3(xb0, 1), 256, 0, stream>>>(featsb, nbr0, wt[0], yraw, s[0], N0, xb0);
  bn_relu_bf16<8><<<bgrid(N0, 8), 256, 0, stream>>>(yraw, s[0], g[0], b[0], nullptr, c0f, N0, i0);

  // conv1: 8->16 down to N1
  conv_mfma<8, 16><<<dim3(xb1, 1), 256, 0, stream>>>(c0f, nbr_d01, wt[1], yraw, s[1], N1, xb1);
  bn_relu_bf16<16><<<bgrid(N1, 16), 256, 0, stream>>>(yraw, s[1], g[1], b[1], nullptr, t1, N1, i1);

  // conv2: 16->16 @ N1
  conv_mfma<16, 16><<<dim3(xb1, 1), 256, 0, stream>>>(t1, nbr1, wt[2], yraw, s[2], N1, xb1);
  bn_relu_bf16<16><<<bgrid(N1, 16), 256, 0, stream>>>(yraw, s[2], g[2], b[2], nullptr, c2f, N1, i1);

  // conv3: 16->32 down to N2
  conv_mfma<16, 32><<<dim3(xb2, 2), 256, 0, stream>>>(c2f, nbr_d12, wt[3], yraw, s[3], N2, xb2);
  bn_relu_bf16<32><<<bgrid(N2, 32), 256, 0, stream>>>(yraw, s[3], g[3], b[3], nullptr, t2, N2, i2);

  // conv4: 32->32 @ N2
  conv_mfma<32, 32><<<dim3(xb2, 2), 256, 0, stream>>>(t2, nbr2, wt[4], yraw, s[4], N2, xb2);
  bn_relu_bf16<32><<<bgrid(N2, 32), 256, 0, stream>>>(yraw, s[4], g[4], b[4], nullptr, c4f, N2, i2);

  // conv5: 32->64 down to N3
  conv_mfma<32, 64><<<dim3(xb3, 4), 256, 0, stream>>>(c4f, nbr_d23, wt[5], yraw, s[5], N3, xb3);
  bn_relu_bf16<64><<<bgrid(N3, 64), 256, 0, stream>>>(yraw, s[5], g[5], b[5], nullptr, t3, N3, i3);

  // conv6: 64->64 @ N3
  conv_mfma<64, 64><<<dim3(xb3, 4), 256, 0, stream>>>(t3, nbr3, wt[6], yraw, s[6], N3, xb3);
  bn_relu_bf16<64><<<bgrid(N3, 64), 256, 0, stream>>>(yraw, s[6], g[6], b[6], nullptr, t4, N3, i3);

  // conv7: 64->32 up to N2; x2 = c4f + relu(bn(y7))
  conv_mfma<64, 32><<<dim3(xb2, 2), 256, 0, stream>>>(t4, nbr_u32, wt[7], yraw, s[7], N2, xb2);
  bn_relu_bf16<32><<<bgrid(N2, 32), 256, 0, stream>>>(yraw, s[7], g[7], b[7], c4f, t5, N2, i2);

  // conv8: 32->16 up to N1; x1 = c2f + relu(bn(y8))
  conv_mfma<32, 16><<<dim3(xb1, 1), 256, 0, stream>>>(t5, nbr_u21, wt[8], yraw, s[8], N1, xb1);
  bn_relu_bf16<16><<<bgrid(N1, 16), 256, 0, stream>>>(yraw, s[8], g[8], b[8], c2f, t6, N1, i1);

  // conv9: 16->8 up to N0; y9 bf16 in yraw
  conv_mfma<16, 8><<<dim3(xb0, 1), 256, 0, stream>>>(t6, nbr_u10, wt[9], yraw, s[9], N0, xb0);

  // tail: x0 = c0f + relu(bn(y9)); out0 = x0 @ lin_w.T
  tail_kernel<<<cdiv(N0, 256), 256, 0, stream>>>(c0f, s[9], g[9], b[9], i0, lin_w, yraw, out0, x0, N0);
}

// Round 12
// 479.973 us; speedup vs baseline: 1.1226x; 1.1226x over previous
//
#include <hip/hip_runtime.h>

#define EPSV 1e-5f

typedef __attribute__((ext_vector_type(8))) short short8;
typedef __attribute__((ext_vector_type(4))) float float4v;

static inline int cdiv(int a, int b) { return (a + b - 1) / b; }
static inline int imin(int a, int b) { return a < b ? a : b; }

__device__ inline unsigned short f2bf(float x) {
  unsigned u = __float_as_uint(x);
  return (unsigned short)((u + 0x7FFFu + ((u >> 16) & 1u)) >> 16);
}
__device__ inline float bf2f(unsigned short u) {
  return __uint_as_float(((unsigned)u) << 16);
}

#define NBUCKET 64

struct PrepArgs {
  const float* w[10];
  unsigned short* wt[10];
  int ci[10];
  int co[10];
  int wcum[11];
  const float* feats;
  unsigned short* featsb;
  int nfeat4;
  float* stats;
};

// grid-stride: zero stats + feats fp32->bf16 + weights fp32->bf16 transposed [27][CO][CI]
__global__ __launch_bounds__(256) void prep_kernel(PrepArgs p, long total) {
  const int nstat4 = 10 * NBUCKET * 128 / 4;
  for (long tid0 = (long)blockIdx.x * 256 + threadIdx.x; tid0 < total;
       tid0 += (long)gridDim.x * 256) {
    long tid = tid0;
    if (tid < nstat4) {
      ((float4*)p.stats)[tid] = make_float4(0.f, 0.f, 0.f, 0.f);
      continue;
    }
    tid -= nstat4;
    if (tid < p.nfeat4) {
      float4 v = ((const float4*)p.feats)[tid];
      ushort4 r;
      r.x = f2bf(v.x); r.y = f2bf(v.y); r.z = f2bf(v.z); r.w = f2bf(v.w);
      ((ushort4*)p.featsb)[tid] = r;
      continue;
    }
    tid -= p.nfeat4;
    if (tid >= p.wcum[10]) continue;
    int i = 0;
    while (tid >= p.wcum[i + 1]) ++i;
    int e = (int)(tid - p.wcum[i]);
    int ci = p.ci[i], co = p.co[i];
    int k = e / (ci * co);
    int r = e - k * (ci * co);
    int o = r / ci;
    int c = r - o * ci;
    p.wt[i][((long)k * co + o) * ci + c] = f2bf(p.w[i][((long)k * ci + c) * co + o]);
  }
}

// ================= MFMA gather-GEMM conv, persistent grid-stride blocks =================
// Block = 4 waves; wave handles one 16-row MFMA tile per 64-row block-tile, looping
// tiles with stride gridDim.x. B fragments hoisted across tiles for CI<=16.
// BN sum/sumsq accumulated in registers across tiles; one atomic pair per wave.
template<int CI, int CO>
__global__ __launch_bounds__(256) void conv_mfma(
    const unsigned short* __restrict__ f, const int* __restrict__ nbr,
    const unsigned short* __restrict__ wt, unsigned short* __restrict__ y,
    float* __restrict__ stats, int nout, int ntiles) {
  constexpr int NCHUNK = (CI == 8) ? 7 : (CI == 16) ? 14 : (CI == 32) ? 27 : 54;

  const int tid = threadIdx.x;
  const int lane = tid & 63;
  const int wid = tid >> 6;
  const int m = lane & 15;
  const int quad = lane >> 4;
  const int cbase = blockIdx.y * 16;
  const int co = cbase + m;
  const bool cok = co < CO;

  auto tapof = [&](int c) -> int {
    if constexpr (CI == 8) return c * 4 + quad;
    else if constexpr (CI == 16) return c * 2 + (quad >> 1);
    else if constexpr (CI == 32) return c;
    else return c >> 1;
  };
  auto cioof = [&](int c) -> int {
    if constexpr (CI == 8) return 0;
    else if constexpr (CI == 16) return (quad & 1) * 8;
    else if constexpr (CI == 32) return quad * 8;
    else return ((c & 1) << 5) + quad * 8;
  };

  float sum = 0.f, sq = 0.f;

  if constexpr (CI <= 16) {
    // ---- B loaded once per wave, reused for every tile ----
    short8 Bv[NCHUNK];
#pragma unroll
    for (int c = 0; c < NCHUNK; ++c) {
      int tap = tapof(c);
      short8 bq;
#pragma unroll
      for (int q = 0; q < 8; ++q) bq[q] = 0;
      if (cok && tap < 27) bq = *(const short8*)(wt + ((long)tap * CO + co) * CI + cioof(c));
      Bv[c] = bq;
    }
    for (int tile = blockIdx.x; tile < ntiles; tile += gridDim.x) {
      const int rowb = tile * 64 + wid * 16;
      const int row = rowb + m;
      const bool rok = row < nout;
      int idxs[NCHUNK];
#pragma unroll
      for (int c = 0; c < NCHUNK; ++c) {
        int tap = tapof(c);
        idxs[c] = (rok && tap < 27) ? nbr[(long)row * 27 + tap] : -1;
      }
      short8 A[NCHUNK];
#pragma unroll
      for (int c = 0; c < NCHUNK; ++c) {
        short8 a;
#pragma unroll
        for (int q = 0; q < 8; ++q) a[q] = 0;
        if (idxs[c] >= 0) a = *(const short8*)(f + (long)idxs[c] * CI + cioof(c));
        A[c] = a;
      }
      float4v acc = {0.f, 0.f, 0.f, 0.f};
#pragma unroll
      for (int c = 0; c < NCHUNK; ++c)
        acc = __builtin_amdgcn_mfma_f32_16x16x32_bf16(A[c], Bv[c], acc, 0, 0, 0);
#pragma unroll
      for (int r = 0; r < 4; ++r) {
        float v = acc[r];
        int orow = rowb + quad * 4 + r;
        if (cok && orow < nout) y[(long)orow * CO + co] = f2bf(v);
        sum += v;
        sq = fmaf(v, v, sq);
      }
    }
  } else {
    constexpr int G = 9;
    constexpr int NG = NCHUNK / G;
    for (int tile = blockIdx.x; tile < ntiles; tile += gridDim.x) {
      const int rowb = tile * 64 + wid * 16;
      const int row = rowb + m;
      const bool rok = row < nout;
      int idxs[27];
#pragma unroll
      for (int t = 0; t < 27; ++t)
        idxs[t] = rok ? nbr[(long)row * 27 + t] : -1;

      short8 A[2][G], B[2][G];
      auto load_group = [&](int g, int bi) {
#pragma unroll
        for (int j = 0; j < G; ++j) {
          const int c = g * G + j;
          const int tap = tapof(c);
          short8 a, bq;
#pragma unroll
          for (int q = 0; q < 8; ++q) { a[q] = 0; bq[q] = 0; }
          int idx = idxs[tap];
          if (idx >= 0) a = *(const short8*)(f + (long)idx * CI + cioof(c));
          if (cok) bq = *(const short8*)(wt + ((long)tap * CO + co) * CI + cioof(c));
          A[bi][j] = a; B[bi][j] = bq;
        }
      };
      float4v acc = {0.f, 0.f, 0.f, 0.f};
      load_group(0, 0);
#pragma unroll
      for (int g = 0; g < NG; ++g) {
        const int cur = g & 1;
        if (g + 1 < NG) load_group(g + 1, cur ^ 1);
#pragma unroll
        for (int j = 0; j < G; ++j)
          acc = __builtin_amdgcn_mfma_f32_16x16x32_bf16(A[cur][j], B[cur][j], acc, 0, 0, 0);
      }
#pragma unroll
      for (int r = 0; r < 4; ++r) {
        float v = acc[r];
        int orow = rowb + quad * 4 + r;
        if (cok && orow < nout) y[(long)orow * CO + co] = f2bf(v);
        sum += v;
        sq = fmaf(v, v, sq);
      }
    }
  }

  // one atomic pair per wave
  sum += __shfl_xor(sum, 16); sq += __shfl_xor(sq, 16);
  sum += __shfl_xor(sum, 32); sq += __shfl_xor(sq, 32);
  if (quad == 0 && cok) {
    float* st = stats + ((((unsigned)blockIdx.x * 4 + wid) & (NBUCKET - 1)) << 7);
    atomicAdd(&st[co], sum);
    atomicAdd(&st[64 + co], sq);
  }
}

// ---- BN+ReLU (+bf16 skip), bf16 y -> bf16 feature map, grid-stride ----
template<int CO>
__global__ __launch_bounds__(256) void bn_relu_bf16(
    const unsigned short* __restrict__ y, const float* __restrict__ stats,
    const float* __restrict__ g, const float* __restrict__ b,
    const unsigned short* __restrict__ skip, unsigned short* __restrict__ out,
    int nout, float inv_n) {
  __shared__ float sA[CO], sC[CO];
  if ((int)threadIdx.x < CO) {
    int o = threadIdx.x;
    float su = 0.f, sq = 0.f;
#pragma unroll 8
    for (int bk = 0; bk < NBUCKET; ++bk) {
      su += stats[bk * 128 + o];
      sq += stats[bk * 128 + 64 + o];
    }
    float mu = su * inv_n;
    float var = sq * inv_n - mu * mu;
    float a = g[o] * rsqrtf(var + EPSV);
    sA[o] = a;
    sC[o] = fmaf(-mu, a, b[o]);
  }
  __syncthreads();
  long total4 = (long)nout * CO / 4;
  for (long i4 = (long)blockIdx.x * 256 + threadIdx.x; i4 < total4;
       i4 += (long)gridDim.x * 256) {
    int o = (int)((i4 * 4) % CO);
    ushort4 v = ((const ushort4*)y)[i4];
    float vv[4] = {bf2f(v.x), bf2f(v.y), bf2f(v.z), bf2f(v.w)};
    unsigned short rr[4];
#pragma unroll
    for (int j = 0; j < 4; ++j) {
      float x = fmaxf(fmaf(vv[j], sA[o + j], sC[o + j]), 0.f);
      if (skip) x += bf2f(skip[i4 * 4 + j]);
      rr[j] = f2bf(x);
    }
    ushort4 r;
    r.x = rr[0]; r.y = rr[1]; r.z = rr[2]; r.w = rr[3];
    ((ushort4*)out)[i4] = r;
  }
}

// ---- fused tail: x0 = c0f + relu(bn(y9)); out0 = x0 @ lin_w.T, grid-stride ----
__global__ __launch_bounds__(256) void tail_kernel(
    const unsigned short* __restrict__ c0f, const float* __restrict__ st9,
    const float* __restrict__ g9, const float* __restrict__ b9, float inv_n,
    const float* __restrict__ lin_w, const unsigned short* __restrict__ y9,
    float* __restrict__ out0, float* __restrict__ x0, int n0) {
  __shared__ float swl[64];
  __shared__ float sbn[16];
  if (threadIdx.x < 64) swl[threadIdx.x] = lin_w[threadIdx.x];
  if (threadIdx.x < 8) {
    int o = threadIdx.x;
    float su = 0.f, sq = 0.f;
#pragma unroll 8
    for (int bk = 0; bk < NBUCKET; ++bk) {
      su += st9[bk * 128 + o];
      sq += st9[bk * 128 + 64 + o];
    }
    float mu = su * inv_n;
    float var = sq * inv_n - mu * mu;
    float a = g9[o] * rsqrtf(var + EPSV);
    sbn[o] = a;
    sbn[8 + o] = fmaf(-mu, a, b9[o]);
  }
  __syncthreads();
  for (int n = blockIdx.x * 256 + threadIdx.x; n < n0; n += gridDim.x * 256) {
    const ushort4* pr = (const ushort4*)(y9 + (long)n * 8);
    ushort4 r0 = pr[0], r1 = pr[1];
    unsigned short rw[8] = {r0.x, r0.y, r0.z, r0.w, r1.x, r1.y, r1.z, r1.w};
    const ushort4* pc = (const ushort4*)(c0f + (long)n * 8);
    ushort4 c0 = pc[0], c1 = pc[1];
    unsigned short cs[8] = {c0.x, c0.y, c0.z, c0.w, c1.x, c1.y, c1.z, c1.w};
    float xv[8];
#pragma unroll
    for (int c = 0; c < 8; ++c)
      xv[c] = bf2f(cs[c]) + fmaxf(fmaf(bf2f(rw[c]), sbn[c], sbn[8 + c]), 0.f);
    *(float4*)(x0 + (long)n * 8) = make_float4(xv[0], xv[1], xv[2], xv[3]);
    *(float4*)(x0 + (long)n * 8 + 4) = make_float4(xv[4], xv[5], xv[6], xv[7]);
    float ov[8];
#pragma unroll
    for (int j = 0; j < 8; ++j) {
      float s = 0.f;
#pragma unroll
      for (int c = 0; c < 8; ++c) s = fmaf(xv[c], swl[j * 8 + c], s);
      ov[j] = s;
    }
    *(float4*)(out0 + (long)n * 8) = make_float4(ov[0], ov[1], ov[2], ov[3]);
    *(float4*)(out0 + (long)n * 8 + 4) = make_float4(ov[4], ov[5], ov[6], ov[7]);
  }
}

extern "C" void kernel_launch(void* const* d_in, const int* in_sizes, int n_in,
                              void* d_out, int out_size, void* d_ws, size_t ws_size,
                              hipStream_t stream) {
  const float* feats   = (const float*)d_in[0];
  const int* nbr0      = (const int*)d_in[1];
  const int* nbr_d01   = (const int*)d_in[2];
  const int* nbr1      = (const int*)d_in[3];
  const int* nbr_d12   = (const int*)d_in[4];
  const int* nbr2      = (const int*)d_in[5];
  const int* nbr_d23   = (const int*)d_in[6];
  const int* nbr3      = (const int*)d_in[7];
  const int* nbr_u32   = (const int*)d_in[8];
  const int* nbr_u21   = (const int*)d_in[9];
  const int* nbr_u10   = (const int*)d_in[10];
  const float* w[10];
  const float* g[10];
  const float* b[10];
  for (int i = 0; i < 10; ++i) {
    w[i] = (const float*)d_in[11 + 3 * i];
    g[i] = (const float*)d_in[12 + 3 * i];
    b[i] = (const float*)d_in[13 + 3 * i];
  }
  const float* lin_w = (const float*)d_in[41];

  const int N0 = in_sizes[0] / 16;
  const int N1 = in_sizes[2] / 27;
  const int N2 = in_sizes[4] / 27;
  const int N3 = in_sizes[6] / 27;
  const float i0 = 1.f / N0, i1 = 1.f / N1, i2 = 1.f / N2, i3 = 1.f / N3;

  static const int CIv[10] = {16, 8, 16, 16, 32, 32, 64, 64, 32, 16};
  static const int COv[10] = {8, 16, 16, 32, 32, 64, 64, 32, 16, 8};

  // ---- workspace: fp32 stats region, then bf16 (ushort) region ----
  float* stats = (float*)d_ws;                       // 10 x NBUCKET x 128 floats
  unsigned short* u = (unsigned short*)(stats + 10 * NBUCKET * 128);

  unsigned short* yraw = u; u += (size_t)N1 * 32;    // bf16 y scratch

  unsigned short* wt[10];
  int wcum[11];
  wcum[0] = 0;
  for (int i = 0; i < 10; ++i) {
    wt[i] = u;
    int sz = 27 * CIv[i] * COv[i];
    u += sz;
    wcum[i + 1] = wcum[i] + sz;
  }
  unsigned short* featsb = u; u += (size_t)N0 * 16;
  unsigned short* c0f = u;    u += (size_t)N0 * 8;
  unsigned short* t1  = u;    u += (size_t)N1 * 16;
  unsigned short* c2f = u;    u += (size_t)N1 * 16;
  unsigned short* t2  = u;    u += (size_t)N2 * 32;
  unsigned short* c4f = u;    u += (size_t)N2 * 32;
  unsigned short* t3  = u;    u += (size_t)N3 * 64;
  unsigned short* t4  = u;    u += (size_t)N3 * 64;
  unsigned short* t5  = t2;   // reuse
  unsigned short* t6  = t1;   // reuse
  float* out0 = (float*)d_out;
  float* x0   = (float*)d_out + (size_t)N0 * 8;

  float* s[10];
  for (int i = 0; i < 10; ++i) s[i] = stats + i * NBUCKET * 128;

  // ---- prep (grid-stride) ----
  PrepArgs pa;
  for (int i = 0; i < 10; ++i) {
    pa.w[i] = w[i]; pa.wt[i] = wt[i];
    pa.ci[i] = CIv[i]; pa.co[i] = COv[i];
    pa.wcum[i] = wcum[i];
  }
  pa.wcum[10] = wcum[10];
  pa.feats = feats; pa.featsb = featsb;
  pa.nfeat4 = N0 * 16 / 4;
  pa.stats = stats;
  long prep_total = (10 * NBUCKET * 128 / 4) + pa.nfeat4 + wcum[10];
  prep_kernel<<<imin((int)((prep_total + 255) / 256), 2048), 256, 0, stream>>>(pa, prep_total);

  auto bgrid = [](long nout, int co) {
    return imin((int)((nout * co / 4 + 255) / 256), 1024);
  };
  auto cgrid = [](int ntiles) { return imin(ntiles, 1024); };

  int tb0 = cdiv(N0, 64), tb1 = cdiv(N1, 64), tb2 = cdiv(N2, 64), tb3 = cdiv(N3, 64);

  // conv0: 16->8 @ N0
  conv_mfma<16, 8><<<dim3(cgrid(tb0), 1), 256, 0, stream>>>(featsb, nbr0, wt[0], yraw, s[0], N0, tb0);
  bn_relu_bf16<8><<<bgrid(N0, 8), 256, 0, stream>>>(yraw, s[0], g[0], b[0], nullptr, c0f, N0, i0);

  // conv1: 8->16 down to N1
  conv_mfma<8, 16><<<dim3(cgrid(tb1), 1), 256, 0, stream>>>(c0f, nbr_d01, wt[1], yraw, s[1], N1, tb1);
  bn_relu_bf16<16><<<bgrid(N1, 16), 256, 0, stream>>>(yraw, s[1], g[1], b[1], nullptr, t1, N1, i1);

  // conv2: 16->16 @ N1
  conv_mfma<16, 16><<<dim3(cgrid(tb1), 1), 256, 0, stream>>>(t1, nbr1, wt[2], yraw, s[2], N1, tb1);
  bn_relu_bf16<16><<<bgrid(N1, 16), 256, 0, stream>>>(yraw, s[2], g[2], b[2], nullptr, c2f, N1, i1);

  // conv3: 16->32 down to N2
  conv_mfma<16, 32><<<dim3(cgrid(tb2), 2), 256, 0, stream>>>(c2f, nbr_d12, wt[3], yraw, s[3], N2, tb2);
  bn_relu_bf16<32><<<bgrid(N2, 32), 256, 0, stream>>>(yraw, s[3], g[3], b[3], nullptr, t2, N2, i2);

  // conv4: 32->32 @ N2
  conv_mfma<32, 32><<<dim3(cgrid(tb2), 2), 256, 0, stream>>>(t2, nbr2, wt[4], yraw, s[4], N2, tb2);
  bn_relu_bf16<32><<<bgrid(N2, 32), 256, 0, stream>>>(yraw, s[4], g[4], b[4], nullptr, c4f, N2, i2);

  // conv5: 32->64 down to N3
  conv_mfma<32, 64><<<dim3(cgrid(tb3), 4), 256, 0, stream>>>(c4f, nbr_d23, wt[5], yraw, s[5], N3, tb3);
  bn_relu_bf16<64><<<bgrid(N3, 64), 256, 0, stream>>>(yraw, s[5], g[5], b[5], nullptr, t3, N3, i3);

  // conv6: 64->64 @ N3
  conv_mfma<64, 64><<<dim3(cgrid(tb3), 4), 256, 0, stream>>>(t3, nbr3, wt[6], yraw, s[6], N3, tb3);
  bn_relu_bf16<64><<<bgrid(N3, 64), 256, 0, stream>>>(yraw, s[6], g[6], b[6], nullptr, t4, N3, i3);

  // conv7: 64->32 up to N2; x2 = c4f + relu(bn(y7))
  conv_mfma<64, 32><<<dim3(cgrid(tb2), 2), 256, 0, stream>>>(t4, nbr_u32, wt[7], yraw, s[7], N2, tb2);
  bn_relu_bf16<32><<<bgrid(N2, 32), 256, 0, stream>>>(yraw, s[7], g[7], b[7], c4f, t5, N2, i2);

  // conv8: 32->16 up to N1; x1 = c2f + relu(bn(y8))
  conv_mfma<32, 16><<<dim3(cgrid(tb1), 1), 256, 0, stream>>>(t5, nbr_u21, wt[8], yraw, s[8], N1, tb1);
  bn_relu_bf16<16><<<bgrid(N1, 16), 256, 0, stream>>>(yraw, s[8], g[8], b[8], c2f, t6, N1, i1);

  // conv9: 16->8 up to N0; y9 bf16 in yraw
  conv_mfma<16, 8><<<dim3(cgrid(tb0), 1), 256, 0, stream>>>(t6, nbr_u10, wt[9], yraw, s[9], N0, tb0);

  // tail: x0 = c0f + relu(bn(y9)); out0 = x0 @ lin_w.T
  tail_kernel<<<imin(cdiv(N0, 256), 1024), 256, 0, stream>>>(
      c0f, s[9], g[9], b[9], i0, lin_w, yraw, out0, x0, N0);
}